// Round 1
// baseline (212.895 us; speedup 1.0000x reference)
//
#include <hip/hip_runtime.h>

// Loss = sum over 4 Haar subbands of mean(|dwt(pred)-dwt(target)|) on
// [32,3,512,512] fp32. DWT linear -> e = pred - target. Per 2x2 block
// (a b / c d), using |x+y|+|x-y| = 2*max(|x|,|y|):
//   contribution = 2*(max(|a+b|,|c+d|) + max(|a-b|,|c-d|))
// The 2 cancels the 0.5 DWT norm -> final scale 1/(32*3*256*256).
//
// R5 (this round): discriminating experiment between
//   (a) fill-writeback-drain contention (external, harness fills drain
//       ~800MB into our window -> kernel changes can't help), and
//   (b) kernel lifecycle limits (burst-load/wait/exit, 12288 waves vs
//       8192 capacity churn, NT loads forbidding cache residency).
// Changes: 1024 persistent blocks (24 rowpairs = 96KiB/tensor each, all
// resident, zero churn), explicit next-step prefetch keeping 4-8 loads
// in flight continuously, plain (cacheable) loads instead of NT.
// Predicted: (b) -> dur ~170us; (a) -> dur unchanged ~190us => roofline.

#define IMG_W        512
#define ROWPAIRS     (32 * 3 * 256)            // 24,576 rowpairs total
#define NUM_BLOCKS   1024
#define BLOCK_SIZE   256
#define RP_PER_BLK   (ROWPAIRS / NUM_BLOCKS)   // 24 rowpairs = 96 KiB/tensor
#define STEPS        (RP_PER_BLK / 2)          // 12 steps of 2 rowpairs
#define STEP_FLOATS  (2 * 2 * IMG_W)           // 2048 floats per step
#define N_SUB        6291456.0f

typedef float vfloat4 __attribute__((ext_vector_type(4)));

__device__ __forceinline__ vfloat4 ld4(const float* p) {
    return *(const vfloat4*)p;
}

__global__ __launch_bounds__(BLOCK_SIZE) void dwt_partial_kernel(
    const float* __restrict__ pred,
    const float* __restrict__ target,
    float* __restrict__ partials)
{
    // Block owns rowpairs [rp0, rp0+24), a contiguous 96 KiB slab per
    // tensor. Each step covers 2 rowpairs (256 threads = 2 rowpairs x
    // 128 float4-cols); each wave-load is 1 KiB contiguous.
    const int rp0  = blockIdx.x * RP_PER_BLK;
    const int rsel = threadIdx.x >> 7;         // which rowpair of the step
    const int j    = threadIdx.x & 127;        // float4 column
    int o = (rp0 + rsel) * (2 * IMG_W) + (j << 2);

    // Pipeline prologue: step 0 loads in flight.
    vfloat4 pe = ld4(pred + o);
    vfloat4 po = ld4(pred + o + IMG_W);
    vfloat4 te = ld4(target + o);
    vfloat4 to = ld4(target + o + IMG_W);

    float acc = 0.0f;

    #pragma unroll
    for (int s = 0; s < STEPS; ++s) {
        // Prefetch next step before consuming current one: keeps the
        // VMEM queue non-empty for the block's whole lifetime.
        vfloat4 npe, npo, nte, nto;
        if (s < STEPS - 1) {
            const int no = o + STEP_FLOATS;
            npe = ld4(pred + no);
            npo = ld4(pred + no + IMG_W);
            nte = ld4(target + no);
            nto = ld4(target + no + IMG_W);
        }

        // Two 2x2 quads per thread per step.
        {
            const float a0 = pe.x - te.x, b0 = pe.y - te.y;
            const float c0 = po.x - to.x, d0 = po.y - to.y;
            acc += fmaxf(fabsf(a0 + b0), fabsf(c0 + d0))
                 + fmaxf(fabsf(a0 - b0), fabsf(c0 - d0));
            const float a1 = pe.z - te.z, b1 = pe.w - te.w;
            const float c1 = po.z - to.z, d1 = po.w - to.w;
            acc += fmaxf(fabsf(a1 + b1), fabsf(c1 + d1))
                 + fmaxf(fabsf(a1 - b1), fabsf(c1 - d1));
        }

        pe = npe; po = npo; te = nte; to = nto;
        o += STEP_FLOATS;
    }

    // 64-lane shuffle reduction
    #pragma unroll
    for (int off = 32; off > 0; off >>= 1)
        acc += __shfl_down(acc, off, 64);

    __shared__ float wave_sums[BLOCK_SIZE / 64];
    const int lane = threadIdx.x & 63;
    const int wid  = threadIdx.x >> 6;
    if (lane == 0) wave_sums[wid] = acc;
    __syncthreads();

    if (threadIdx.x == 0)
        partials[blockIdx.x] = wave_sums[0] + wave_sums[1]
                             + wave_sums[2] + wave_sums[3];
}

__global__ __launch_bounds__(BLOCK_SIZE) void dwt_final_kernel(
    const float* __restrict__ partials,
    float* __restrict__ out)
{
    float acc = 0.0f;
    #pragma unroll
    for (int k = 0; k < NUM_BLOCKS / BLOCK_SIZE; ++k)
        acc += partials[threadIdx.x + k * BLOCK_SIZE];

    #pragma unroll
    for (int off = 32; off > 0; off >>= 1)
        acc += __shfl_down(acc, off, 64);

    __shared__ float wave_sums[BLOCK_SIZE / 64];
    const int lane = threadIdx.x & 63;
    const int wid  = threadIdx.x >> 6;
    if (lane == 0) wave_sums[wid] = acc;
    __syncthreads();

    if (threadIdx.x == 0)
        out[0] = (wave_sums[0] + wave_sums[1] + wave_sums[2] + wave_sums[3])
               * (1.0f / N_SUB);
}

extern "C" void kernel_launch(void* const* d_in, const int* in_sizes, int n_in,
                              void* d_out, int out_size, void* d_ws, size_t ws_size,
                              hipStream_t stream)
{
    const float* pred   = (const float*)d_in[0];
    const float* target = (const float*)d_in[1];
    float* partials     = (float*)d_ws;    // 1024 floats = 4 KB
    float* out          = (float*)d_out;

    dwt_partial_kernel<<<NUM_BLOCKS, BLOCK_SIZE, 0, stream>>>(pred, target, partials);
    dwt_final_kernel<<<1, BLOCK_SIZE, 0, stream>>>(partials, out);
}

// Round 2
// 210.442 us; speedup vs baseline: 1.0117x; 1.0117x over previous
//
#include <hip/hip_runtime.h>

// Loss = sum over 4 Haar subbands of mean(|dwt(pred)-dwt(target)|) on
// [32,3,512,512] fp32. DWT linear -> e = pred - target. Per 2x2 block
// (a b / c d), using |x+y|+|x-y| = 2*max(|x|,|y|):
//   contribution = 2*(max(|a+b|,|c+d|) + max(|a-b|,|c-d|))
// The 2 cancels the 0.5 DWT norm -> final scale 1/(32*3*256*256).
//
// R6: R5 falsified the writeback-drain theory (repeat dispatches read
// 201MB entirely from L3, hbm_bytes~0, still 75us = 2.7 TB/s). R5 also
// showed occupancy is first-order: 16 waves/CU -> 2.7 TB/s vs R0's
// 32 waves/CU -> >=3.4 TB/s. This round: 2048 blocks (exactly 8
// blocks/CU = 2048 thr/CU residency cap, zero churn) + prefetch depth 2
// (8 float4 loads in flight/thread, VGPR<=64 so 8 waves/SIMD holds).
// Predicted: kernel ~52-57us (3.7 TB/s) if concurrency-bound; if it
// stays ~75us at full occupancy, 2.7 TB/s is the L3-read ceiling and
// the region floor (fills 118.8 + kernel + final + gaps) is ~208us.

#define IMG_W        512
#define ROWPAIRS     (32 * 3 * 256)            // 24,576 rowpairs total
#define NUM_BLOCKS   2048
#define BLOCK_SIZE   256
#define RP_PER_BLK   (ROWPAIRS / NUM_BLOCKS)   // 12 rowpairs = 48 KiB/tensor
#define STEPS        (RP_PER_BLK / 2)          // 6 steps of 2 rowpairs
#define STEP_FLOATS  (2 * 2 * IMG_W)           // 2048 floats per step
#define N_SUB        6291456.0f

typedef float vfloat4 __attribute__((ext_vector_type(4)));

__device__ __forceinline__ vfloat4 ld4(const float* p) {
    return *(const vfloat4*)p;
}

__global__ __launch_bounds__(BLOCK_SIZE) void dwt_partial_kernel(
    const float* __restrict__ pred,
    const float* __restrict__ target,
    float* __restrict__ partials)
{
    // Block owns rowpairs [rp0, rp0+12), a contiguous 48 KiB slab per
    // tensor. Each step covers 2 rowpairs (256 threads = 2 rowpairs x
    // 128 float4-cols); each wave-load is 1 KiB contiguous.
    const int rp0  = blockIdx.x * RP_PER_BLK;
    const int rsel = threadIdx.x >> 7;         // which rowpair of the step
    const int j    = threadIdx.x & 127;        // float4 column
    const int base = (rp0 + rsel) * (2 * IMG_W) + (j << 2);

    // Pipeline prologue: steps 0 and 1 in flight (8 loads/thread).
    vfloat4 pe0 = ld4(pred + base);
    vfloat4 po0 = ld4(pred + base + IMG_W);
    vfloat4 te0 = ld4(target + base);
    vfloat4 to0 = ld4(target + base + IMG_W);

    const int b1 = base + STEP_FLOATS;
    vfloat4 pe1 = ld4(pred + b1);
    vfloat4 po1 = ld4(pred + b1 + IMG_W);
    vfloat4 te1 = ld4(target + b1);
    vfloat4 to1 = ld4(target + b1 + IMG_W);

    float acc = 0.0f;
    int o = base;

    #pragma unroll
    for (int s = 0; s < STEPS; ++s) {
        // Prefetch step s+2: keeps ~8 loads in flight per thread for
        // the block's whole lifetime.
        vfloat4 npe, npo, nte, nto;
        if (s < STEPS - 2) {
            const int no = o + 2 * STEP_FLOATS;
            npe = ld4(pred + no);
            npo = ld4(pred + no + IMG_W);
            nte = ld4(target + no);
            nto = ld4(target + no + IMG_W);
        }

        // Consume step s: two 2x2 quads per thread.
        {
            const float a0 = pe0.x - te0.x, b0 = pe0.y - te0.y;
            const float c0 = po0.x - to0.x, d0 = po0.y - to0.y;
            acc += fmaxf(fabsf(a0 + b0), fabsf(c0 + d0))
                 + fmaxf(fabsf(a0 - b0), fabsf(c0 - d0));
            const float a1 = pe0.z - te0.z, b1q = pe0.w - te0.w;
            const float c1 = po0.z - to0.z, d1 = po0.w - to0.w;
            acc += fmaxf(fabsf(a1 + b1q), fabsf(c1 + d1))
                 + fmaxf(fabsf(a1 - b1q), fabsf(c1 - d1));
        }

        // Shift pipeline (register renaming under full unroll).
        pe0 = pe1; po0 = po1; te0 = te1; to0 = to1;
        pe1 = npe; po1 = npo; te1 = nte; to1 = nto;
        o += STEP_FLOATS;
    }

    // 64-lane shuffle reduction
    #pragma unroll
    for (int off = 32; off > 0; off >>= 1)
        acc += __shfl_down(acc, off, 64);

    __shared__ float wave_sums[BLOCK_SIZE / 64];
    const int lane = threadIdx.x & 63;
    const int wid  = threadIdx.x >> 6;
    if (lane == 0) wave_sums[wid] = acc;
    __syncthreads();

    if (threadIdx.x == 0)
        partials[blockIdx.x] = wave_sums[0] + wave_sums[1]
                             + wave_sums[2] + wave_sums[3];
}

__global__ __launch_bounds__(BLOCK_SIZE) void dwt_final_kernel(
    const float* __restrict__ partials,
    float* __restrict__ out)
{
    float acc = 0.0f;
    #pragma unroll
    for (int k = 0; k < NUM_BLOCKS / BLOCK_SIZE; ++k)
        acc += partials[threadIdx.x + k * BLOCK_SIZE];

    #pragma unroll
    for (int off = 32; off > 0; off >>= 1)
        acc += __shfl_down(acc, off, 64);

    __shared__ float wave_sums[BLOCK_SIZE / 64];
    const int lane = threadIdx.x & 63;
    const int wid  = threadIdx.x >> 6;
    if (lane == 0) wave_sums[wid] = acc;
    __syncthreads();

    if (threadIdx.x == 0)
        out[0] = (wave_sums[0] + wave_sums[1] + wave_sums[2] + wave_sums[3])
               * (1.0f / N_SUB);
}

extern "C" void kernel_launch(void* const* d_in, const int* in_sizes, int n_in,
                              void* d_out, int out_size, void* d_ws, size_t ws_size,
                              hipStream_t stream)
{
    const float* pred   = (const float*)d_in[0];
    const float* target = (const float*)d_in[1];
    float* partials     = (float*)d_ws;    // 2048 floats = 8 KB
    float* out          = (float*)d_out;

    dwt_partial_kernel<<<NUM_BLOCKS, BLOCK_SIZE, 0, stream>>>(pred, target, partials);
    dwt_final_kernel<<<1, BLOCK_SIZE, 0, stream>>>(partials, out);
}

// Round 3
// 190.839 us; speedup vs baseline: 1.1156x; 1.1027x over previous
//
#include <hip/hip_runtime.h>

// Loss = sum over 4 Haar subbands of mean(|dwt(pred)-dwt(target)|) on
// [32,3,512,512] fp32. DWT linear -> e = pred - target. Per 2x2 block
// (a b / c d), using |x+y|+|x-y| = 2*max(|x|,|y|):
//   contribution = 2*(max(|a+b|,|c+d|) + max(|a-b|,|c-d|))
// The 2 cancels the 0.5 DWT norm -> final scale 1/(32*3*256*256).
//
// History: R0 config (3072 blks, 32KiB slabs, NT loads, pred-burst->
// target-burst) = 191.7us total (~55us kernel, 3.65 TB/s). R5/R6
// (plain loads, interleaved p/t, 1024/2048 blks) = 74us kernel pinned
// at 2.7 TB/s regardless of occupancy (16 vs 32 waves/CU), prefetch
// depth, or data residency (L3 vs HBM). Conclusion: concurrency is not
// the limiter; the R0 ingredients are load-bearing.
//
// R7: restore R0 exactly + ONE new variable: per-block phase rotation.
// Theory: all blocks progress in lockstep through 32KiB slabs whose
// stride is a multiple of any pow2 channel supercycle -> at any instant
// all 3072 blocks hit the same channel subset (and pred/target are
// 96MiB apart = same channel), serializing on per-channel BW. Block b
// starts its 4-step sweep at step (b&3), spreading the population over
// 4 phases 8KiB apart. Predict: hotspot right -> kernel 42-48us, dur
// 178-186; hotspot wrong -> dur ~192 (restored R0 floor).

#define IMG_W        512
#define ROWPAIRS     (32 * 3 * 256)            // 24,576 rowpairs total
#define NUM_BLOCKS   3072
#define BLOCK_SIZE   256
#define RP_PER_BLK   (ROWPAIRS / NUM_BLOCKS)   // 8 rowpairs = 32 KiB/tensor
#define NSTEPS       (RP_PER_BLK / 2)          // 4 steps of 2 rowpairs
#define STEP_FLOATS  (2 * 2 * IMG_W)           // 2048 floats per step
#define N_SUB        6291456.0f

typedef float vfloat4 __attribute__((ext_vector_type(4)));

__device__ __forceinline__ vfloat4 nt_load4(const float* p) {
    return __builtin_nontemporal_load((const vfloat4*)p);
}

__device__ __forceinline__ float quad_term(vfloat4 pe, vfloat4 po,
                                           vfloat4 te, vfloat4 to) {
    const float a0 = pe.x - te.x, b0 = pe.y - te.y;
    const float c0 = po.x - to.x, d0 = po.y - to.y;
    float r = fmaxf(fabsf(a0 + b0), fabsf(c0 + d0))
            + fmaxf(fabsf(a0 - b0), fabsf(c0 - d0));
    const float a1 = pe.z - te.z, b1 = pe.w - te.w;
    const float c1 = po.z - to.z, d1 = po.w - to.w;
    r += fmaxf(fabsf(a1 + b1), fabsf(c1 + d1))
       + fmaxf(fabsf(a1 - b1), fabsf(c1 - d1));
    return r;
}

__global__ __launch_bounds__(BLOCK_SIZE) void dwt_partial_kernel(
    const float* __restrict__ pred,
    const float* __restrict__ target,
    float* __restrict__ partials)
{
    // Block owns rowpairs [rp0, rp0+8): contiguous 32 KiB slab per
    // tensor, swept in 4 steps of 2 rowpairs. Step order is rotated by
    // (blockIdx & 3) to decorrelate the instantaneous channel phase
    // across the block population. Within a step: pred burst (8 KiB
    // block-wide) then target burst, nontemporal.
    const int rp0   = blockIdx.x * RP_PER_BLK;
    const int rsel  = threadIdx.x >> 7;        // rowpair within step
    const int j     = threadIdx.x & 127;       // float4 column
    const int rot   = blockIdx.x & (NSTEPS - 1);
    const int tbase = (rp0 + rsel) * (2 * IMG_W) + (j << 2);

    // Prologue: issue step 'rot' (4 loads in flight).
    int o = tbase + rot * STEP_FLOATS;
    vfloat4 pe = nt_load4(pred + o);
    vfloat4 po = nt_load4(pred + o + IMG_W);
    vfloat4 te = nt_load4(target + o);
    vfloat4 to = nt_load4(target + o + IMG_W);

    float acc = 0.0f;

    #pragma unroll
    for (int s = 0; s < NSTEPS; ++s) {
        // Prefetch next (rotated) step: 4-8 loads in flight steady-state.
        vfloat4 npe, npo, nte, nto;
        if (s < NSTEPS - 1) {
            const int pn = (s + 1 + rot) & (NSTEPS - 1);
            const int no = tbase + pn * STEP_FLOATS;
            npe = nt_load4(pred + no);
            npo = nt_load4(pred + no + IMG_W);
            nte = nt_load4(target + no);
            nto = nt_load4(target + no + IMG_W);
        }

        acc += quad_term(pe, po, te, to);

        pe = npe; po = npo; te = nte; to = nto;
    }

    // 64-lane shuffle reduction
    #pragma unroll
    for (int off = 32; off > 0; off >>= 1)
        acc += __shfl_down(acc, off, 64);

    __shared__ float wave_sums[BLOCK_SIZE / 64];
    const int lane = threadIdx.x & 63;
    const int wid  = threadIdx.x >> 6;
    if (lane == 0) wave_sums[wid] = acc;
    __syncthreads();

    if (threadIdx.x == 0)
        partials[blockIdx.x] = wave_sums[0] + wave_sums[1]
                             + wave_sums[2] + wave_sums[3];
}

__global__ __launch_bounds__(BLOCK_SIZE) void dwt_final_kernel(
    const float* __restrict__ partials,
    float* __restrict__ out)
{
    float acc = 0.0f;
    #pragma unroll
    for (int k = 0; k < NUM_BLOCKS / BLOCK_SIZE; ++k)
        acc += partials[threadIdx.x + k * BLOCK_SIZE];

    #pragma unroll
    for (int off = 32; off > 0; off >>= 1)
        acc += __shfl_down(acc, off, 64);

    __shared__ float wave_sums[BLOCK_SIZE / 64];
    const int lane = threadIdx.x & 63;
    const int wid  = threadIdx.x >> 6;
    if (lane == 0) wave_sums[wid] = acc;
    __syncthreads();

    if (threadIdx.x == 0)
        out[0] = (wave_sums[0] + wave_sums[1] + wave_sums[2] + wave_sums[3])
               * (1.0f / N_SUB);
}

extern "C" void kernel_launch(void* const* d_in, const int* in_sizes, int n_in,
                              void* d_out, int out_size, void* d_ws, size_t ws_size,
                              hipStream_t stream)
{
    const float* pred   = (const float*)d_in[0];
    const float* target = (const float*)d_in[1];
    float* partials     = (float*)d_ws;    // 3072 floats = 12 KB
    float* out          = (float*)d_out;

    dwt_partial_kernel<<<NUM_BLOCKS, BLOCK_SIZE, 0, stream>>>(pred, target, partials);
    dwt_final_kernel<<<1, BLOCK_SIZE, 0, stream>>>(partials, out);
}